// Round 7
// baseline (492.959 us; speedup 1.0000x reference)
//
#include <hip/hip_runtime.h>
#include <hip/hip_bf16.h>

#define NN 100000
#define NE 300000
#define DD 128
#define NBLKG 782            // ceil(NN/128) gemm blocks
#define NBLKSEG 49           // ceil(NN/2048) scan blocks per segment

typedef short bf16x8 __attribute__((ext_vector_type(8)));
typedef float f32x4 __attribute__((ext_vector_type(4)));

__device__ __forceinline__ unsigned short f2b(float f) {
    union { float f; unsigned u; } c; c.f = f;
    unsigned u = c.u;
    return (unsigned short)((u + 0x7fffu + ((u >> 16) & 1u)) >> 16);
}
__device__ __forceinline__ float b2lo(unsigned u) {
    union { float f; unsigned u; } c; c.u = u << 16; return c.f;
}
__device__ __forceinline__ float b2hi(unsigned u) {
    union { float f; unsigned u; } c; c.u = u & 0xffff0000u; return c.f;
}
// RNE pack of two f32 -> packed bf16x2 (low=lo). Uses hip intrinsic so gfx950
// can lower to v_cvt_pk_bf16_f32 if available; rounding identical to f2b.
__device__ __forceinline__ unsigned pack2(float lo, float hi) {
    __hip_bfloat162 h = __float22bfloat162_rn(make_float2(lo, hi));
    union { __hip_bfloat162 h; unsigned u; } c; c.h = h; return c.u;
}

// ---------- feat -> bf16 ----------
__global__ __launch_bounds__(256) void feat_to_bf16(
    const float* __restrict__ feat, unsigned short* __restrict__ fb) {
    int gid = blockIdx.x * 256 + threadIdx.x;
    if (gid >= NN * 16) return;
    const float4* f4 = (const float4*)feat;
    float4 a = f4[gid * 2], b = f4[gid * 2 + 1];
    uint4 o;
    o.x = pack2(a.x, a.y); o.y = pack2(a.z, a.w);
    o.z = pack2(b.x, b.y); o.w = pack2(b.z, b.w);
    ((uint4*)fb)[gid] = o;
}

// ---------- weight prep ----------
__global__ __launch_bounds__(256) void prep_weights(
    const float* __restrict__ Wl0, const float* __restrict__ bl0, const float* __restrict__ Wr0,
    const float* __restrict__ Wl1, const float* __restrict__ bl1, const float* __restrict__ Wr1,
    const float* __restrict__ Wl2, const float* __restrict__ bl2, const float* __restrict__ Wr2,
    const float* __restrict__ Wla, const float* __restrict__ bla, const float* __restrict__ Wra,
    const float* __restrict__ Wf,  const float* __restrict__ bfv, const float* __restrict__ Wrf,
    const float* __restrict__ wt,
    unsigned short* __restrict__ WcatB, float* __restrict__ bias1,
    unsigned short* __restrict__ W2catB, float* __restrict__ bias2) {
    int idx = blockIdx.x * 256 + threadIdx.x;
    float w0 = wt[0], w1 = wt[1], w2 = wt[2];
    if (idx < 81920) {
        int f = idx / 640, k = idx % 640;   // [f][kcat]
        float v;
        if (k < 128)      v = w0 * Wl0[f * 128 + k];
        else if (k < 256) v = w1 * Wl1[f * 128 + (k - 128)];
        else if (k < 384) v = w2 * Wl2[f * 128 + (k - 256)];
        else if (k < 512) v = Wla[f * 128 + (k - 384)];
        else {
            int kk = k - 512;
            v = w0 * Wr0[f * 128 + kk] + w1 * Wr1[f * 128 + kk] +
                w2 * Wr2[f * 128 + kk] + Wra[f * 128 + kk];
        }
        WcatB[idx] = f2b(v);
    } else if (idx < 81920 + 32768) {
        int j = idx - 81920;
        int f = j >> 8, k = j & 255;        // [f][k], K=256
        W2catB[j] = f2b((k < 128) ? Wf[f * 128 + k] : Wrf[f * 128 + (k - 128)]);
    } else if (idx < 81920 + 32768 + 128) {
        int f = idx - (81920 + 32768);
        bias1[f] = w0 * bl0[f] + w1 * bl1[f] + w2 * bl2[f] + bla[f];
        bias2[f] = bfv[f];
    }
}

// ---------- CSR build ----------
__global__ __launch_bounds__(256) void count_deg(
    const int* __restrict__ e0, const int* __restrict__ e1, const int* __restrict__ e2,
    int* __restrict__ deg) {
    int gid = blockIdx.x * 256 + threadIdx.x;
    if (gid >= 3 * NE) return;
    int t = (gid < NE) ? 0 : ((gid < 2 * NE) ? 1 : 2);
    int i = gid - t * NE;
    const int* ep = (t == 0) ? e0 : ((t == 1) ? e1 : e2);
    atomicAdd(&deg[t * NN + ep[NE + i]], 1);
}

__global__ __launch_bounds__(256) void scan_local(
    const int* __restrict__ deg, int* __restrict__ rowstart, int* __restrict__ bsum) {
    __shared__ int sc[256];
    int b = blockIdx.x, tid = threadIdx.x;
    int seg = b / NBLKSEG, blk = b % NBLKSEG;
    int g0 = seg * NN;
    int base = blk * 2048 + tid * 8;
    int vals[8]; int tsum = 0;
#pragma unroll
    for (int j = 0; j < 8; ++j) {
        int l = base + j;
        int d = (l < NN) ? deg[g0 + l] : 0;
        vals[j] = tsum; tsum += d;
    }
    sc[tid] = tsum;
    __syncthreads();
    for (int off = 1; off < 256; off <<= 1) {
        int v = (tid >= off) ? sc[tid - off] : 0;
        __syncthreads();
        sc[tid] += v;
        __syncthreads();
    }
    int excl = sc[tid] - tsum;
#pragma unroll
    for (int j = 0; j < 8; ++j) {
        int l = base + j;
        if (l < NN) rowstart[g0 + l] = excl + vals[j];
    }
    if (tid == 255) bsum[b] = sc[255];
}

__global__ void scan_bsum(int* __restrict__ bsum) {
    int tid = threadIdx.x;
    if (tid < 3) {
        int run = 0;
        for (int b = 0; b < NBLKSEG; ++b) {
            int idx = tid * NBLKSEG + b;
            int t = bsum[idx]; bsum[idx] = run; run += t;
        }
    }
}

__global__ __launch_bounds__(256) void scan_fix(
    int* __restrict__ rowstart, int* __restrict__ fillpos, const int* __restrict__ bsum) {
    int b = blockIdx.x, tid = threadIdx.x;
    int seg = b / NBLKSEG, blk = b % NBLKSEG;
    int g0 = seg * NN;
    int base = blk * 2048 + tid * 8;
    int off = bsum[b];
#pragma unroll
    for (int j = 0; j < 8; ++j) {
        int l = base + j;
        if (l < NN) {
            int r = rowstart[g0 + l] + off;
            rowstart[g0 + l] = r;
            fillpos[g0 + l] = r;
        }
    }
}

__global__ __launch_bounds__(256) void fill_csr(
    const int* __restrict__ e0, const int* __restrict__ e1, const int* __restrict__ e2,
    int* __restrict__ fillpos, int* __restrict__ csr) {
    int gid = blockIdx.x * 256 + threadIdx.x;
    if (gid >= 3 * NE) return;
    int t = (gid < NE) ? 0 : ((gid < 2 * NE) ? 1 : 2);
    int i = gid - t * NE;
    const int* ep = (t == 0) ? e0 : ((t == 1) ? e1 : e2);
    int src = ep[i], dst = ep[NE + i];
    int p = atomicAdd(&fillpos[t * NN + dst], 1);
    csr[t * NE + p] = src;
}

// ---------- gather1: wave per node, no LDS; writes meanB[n][512] bf16 ----------
__global__ __launch_bounds__(256) void gather1(
    const unsigned short* __restrict__ featB,
    const int* __restrict__ deg, const int* __restrict__ rowstart, const int* __restrict__ csr,
    unsigned short* __restrict__ meanB) {
    int n = (blockIdx.x * 256 + threadIdx.x) >> 6;
    if (n >= NN) return;
    int lane = threadIdx.x & 63, slot = lane >> 4, fq = lane & 15;
    float aA[8] = {0.f, 0.f, 0.f, 0.f, 0.f, 0.f, 0.f, 0.f};
    int dall = 0;
#pragma unroll
    for (int t = 0; t < 3; ++t) {
        int d = deg[t * NN + n];
        int r0 = rowstart[t * NN + n];
        float ac[8] = {0.f, 0.f, 0.f, 0.f, 0.f, 0.f, 0.f, 0.f};
        for (int j = slot; j < d; j += 4) {
            int src = csr[(size_t)t * NE + r0 + j];
            uint4 v = *(const uint4*)(featB + (size_t)src * DD + fq * 8);
            ac[0] += b2lo(v.x); ac[1] += b2hi(v.x);
            ac[2] += b2lo(v.y); ac[3] += b2hi(v.y);
            ac[4] += b2lo(v.z); ac[5] += b2hi(v.z);
            ac[6] += b2lo(v.w); ac[7] += b2hi(v.w);
        }
#pragma unroll
        for (int i = 0; i < 8; ++i) {
            ac[i] += __shfl_xor(ac[i], 16);
            ac[i] += __shfl_xor(ac[i], 32);
            aA[i] += ac[i];
        }
        dall += d;
        if (slot == 0) {
            float inv = 1.0f / fmaxf((float)d, 1.0f);
            uint4 o;
            o.x = pack2(ac[0] * inv, ac[1] * inv);
            o.y = pack2(ac[2] * inv, ac[3] * inv);
            o.z = pack2(ac[4] * inv, ac[5] * inv);
            o.w = pack2(ac[6] * inv, ac[7] * inv);
            *(uint4*)(meanB + (size_t)n * 512 + t * 128 + fq * 8) = o;
        }
    }
    if (slot == 0) {
        float inv = 1.0f / fmaxf((float)dall, 1.0f);
        uint4 o;
        o.x = pack2(aA[0] * inv, aA[1] * inv);
        o.y = pack2(aA[2] * inv, aA[3] * inv);
        o.z = pack2(aA[4] * inv, aA[5] * inv);
        o.w = pack2(aA[6] * inv, aA[7] * inv);
        *(uint4*)(meanB + (size_t)n * 512 + 384 + fq * 8) = o;
    }
}

// ---------- gemm1_tile: [128 x 640] @ [640 x 128] MFMA, BK=64, bias+relu, BN partials ----------
__global__ __launch_bounds__(256) void gemm1_tile(
    const unsigned short* __restrict__ meanB, const unsigned short* __restrict__ featB,
    const unsigned short* __restrict__ WcatB, const float* __restrict__ bias1,
    unsigned short* __restrict__ comb, float* __restrict__ partials) {
    __shared__ unsigned short ABs[16384];   // 32 KB: As [0,8192), Bs [8192,16384)
    unsigned short* As = ABs;               // frag-major: ((s*128+row)*4+q)*8, s in {0,1}
    unsigned short* Bs = ABs + 8192;
    int tid = threadIdx.x;
    int wid = tid >> 6, lane = tid & 63;
    int quad = lane >> 4, m16 = lane & 15;
    int nb = blockIdx.x * 128;
    int mb = (wid & 1) * 64, fb = (wid >> 1) * 64;
    f32x4 acc[4][4];
#pragma unroll
    for (int mi = 0; mi < 4; ++mi)
#pragma unroll
        for (int fi = 0; fi < 4; ++fi) acc[mi][fi] = (f32x4){0.f, 0.f, 0.f, 0.f};

    for (int kc = 0; kc < 10; ++kc) {       // 10 chunks of K=64
        __syncthreads();
#pragma unroll
        for (int it = 0; it < 4; ++it) {    // A: 1024 uint4 items
            int idx = it * 256 + tid;
            int row = idx >> 3, c8 = idx & 7;
            int s = c8 >> 2, q = c8 & 3;
            int gr = min(nb + row, NN - 1);
            uint4 v = (kc < 8)
                ? *(const uint4*)(meanB + (size_t)gr * 512 + kc * 64 + c8 * 8)
                : *(const uint4*)(featB + (size_t)gr * DD + (kc - 8) * 64 + c8 * 8);
            *(uint4*)&As[(((s * 128 + row) * 4) + q) * 8] = v;
        }
#pragma unroll
        for (int it = 0; it < 4; ++it) {    // B
            int idx = it * 256 + tid;
            int f = idx >> 3, c8 = idx & 7;
            int s = c8 >> 2, q = c8 & 3;
            uint4 v = *(const uint4*)(WcatB + (size_t)f * 640 + kc * 64 + c8 * 8);
            *(uint4*)&Bs[(((s * 128 + f) * 4) + q) * 8] = v;
        }
        __syncthreads();
#pragma unroll
        for (int s = 0; s < 2; ++s) {
            bf16x8 av[4], bv[4];
#pragma unroll
            for (int mi = 0; mi < 4; ++mi)
                av[mi] = *(const bf16x8*)&As[(((s * 128 + mb + mi * 16 + m16) * 4) + quad) * 8];
#pragma unroll
            for (int fi = 0; fi < 4; ++fi)
                bv[fi] = *(const bf16x8*)&Bs[(((s * 128 + fb + fi * 16 + m16) * 4) + quad) * 8];
#pragma unroll
            for (int mi = 0; mi < 4; ++mi)
#pragma unroll
                for (int fi = 0; fi < 4; ++fi)
                    acc[mi][fi] = __builtin_amdgcn_mfma_f32_16x16x32_bf16(av[mi], bv[fi], acc[mi][fi], 0, 0, 0);
        }
    }
    __syncthreads();    // reuse LDS for BN partials
    float* bnS = (float*)ABs;
    float* bnQ = bnS + 128;
    if (tid < 128) { bnS[tid] = 0.f; bnQ[tid] = 0.f; }
    __syncthreads();
#pragma unroll
    for (int fi = 0; fi < 4; ++fi) {
        int f = fb + fi * 16 + m16;
        float bb = bias1[f];
        float s = 0.f, q = 0.f;
#pragma unroll
        for (int mi = 0; mi < 4; ++mi) {
#pragma unroll
            for (int r = 0; r < 4; ++r) {
                int row = nb + mb + mi * 16 + quad * 4 + r;
                float v = fmaxf(acc[mi][fi][r] + bb, 0.f);
                if (row < NN) {
                    s += v; q += v * v;
                    comb[(size_t)row * DD + f] = f2b(v);
                }
            }
        }
        atomicAdd(&bnS[f], s);
        atomicAdd(&bnQ[f], q);
    }
    __syncthreads();
    if (tid < 128) {
        partials[(size_t)tid * NBLKG + blockIdx.x] = bnS[tid];
        partials[(size_t)(128 + tid) * NBLKG + blockIdx.x] = bnQ[tid];
    }
}

// ---------- BN finalize ----------
__global__ __launch_bounds__(256) void bnfin(
    const float* __restrict__ partials,
    const float* __restrict__ gamma, const float* __restrict__ beta,
    float* __restrict__ bnA, float* __restrict__ bnB) {
    __shared__ float rs[256], rq[256];
    int f = blockIdx.x, tid = threadIdx.x;
    float s = 0.f, q = 0.f;
    for (int r = tid; r < NBLKG; r += 256) {
        s += partials[(size_t)f * NBLKG + r];
        q += partials[(size_t)(128 + f) * NBLKG + r];
    }
    rs[tid] = s; rq[tid] = q;
    __syncthreads();
    for (int off = 128; off > 0; off >>= 1) {
        if (tid < off) { rs[tid] += rs[tid + off]; rq[tid] += rq[tid + off]; }
        __syncthreads();
    }
    if (tid == 0) {
        float mu = rs[0] / (float)NN;
        float var = fmaxf(rq[0] / (float)NN - mu * mu, 0.f);
        float a = gamma[f] * rsqrtf(var + 1e-5f);
        bnA[f] = a;
        bnB[f] = beta[f] - mu * a;
    }
}

// ---------- gather2: wave per node; mean of BN(comb) rows -> meanC[n][128] bf16 ----------
__global__ __launch_bounds__(256) void gather2(
    const unsigned short* __restrict__ comb,
    const int* __restrict__ deg, const int* __restrict__ rowstart, const int* __restrict__ csr,
    const float* __restrict__ bnA, const float* __restrict__ bnB,
    unsigned short* __restrict__ meanC) {
    int n = (blockIdx.x * 256 + threadIdx.x) >> 6;
    if (n >= NN) return;
    int lane = threadIdx.x & 63, slot = lane >> 4, fq = lane & 15;
    float ac[8] = {0.f, 0.f, 0.f, 0.f, 0.f, 0.f, 0.f, 0.f};
    int dall = 0;
#pragma unroll
    for (int t = 0; t < 3; ++t) {
        int d = deg[t * NN + n];
        int r0 = rowstart[t * NN + n];
        for (int j = slot; j < d; j += 4) {
            int src = csr[(size_t)t * NE + r0 + j];
            uint4 v = *(const uint4*)(comb + (size_t)src * DD + fq * 8);
            ac[0] += b2lo(v.x); ac[1] += b2hi(v.x);
            ac[2] += b2lo(v.y); ac[3] += b2hi(v.y);
            ac[4] += b2lo(v.z); ac[5] += b2hi(v.z);
            ac[6] += b2lo(v.w); ac[7] += b2hi(v.w);
        }
        dall += d;
    }
#pragma unroll
    for (int i = 0; i < 8; ++i) {
        ac[i] += __shfl_xor(ac[i], 16);
        ac[i] += __shfl_xor(ac[i], 32);
    }
    if (slot == 0) {
        float v[8] = {0.f, 0.f, 0.f, 0.f, 0.f, 0.f, 0.f, 0.f};
        if (dall > 0) {
            float inv = 1.0f / (float)dall;
            float4 a0 = *(const float4*)&bnA[fq * 8], a1 = *(const float4*)&bnA[fq * 8 + 4];
            float4 b0 = *(const float4*)&bnB[fq * 8], b1 = *(const float4*)&bnB[fq * 8 + 4];
            v[0] = a0.x * (ac[0] * inv) + b0.x; v[1] = a0.y * (ac[1] * inv) + b0.y;
            v[2] = a0.z * (ac[2] * inv) + b0.z; v[3] = a0.w * (ac[3] * inv) + b0.w;
            v[4] = a1.x * (ac[4] * inv) + b1.x; v[5] = a1.y * (ac[5] * inv) + b1.y;
            v[6] = a1.z * (ac[6] * inv) + b1.z; v[7] = a1.w * (ac[7] * inv) + b1.w;
        }
        uint4 o;
        o.x = pack2(v[0], v[1]); o.y = pack2(v[2], v[3]);
        o.z = pack2(v[4], v[5]); o.w = pack2(v[6], v[7]);
        *(uint4*)(meanC + (size_t)n * DD + fq * 8) = o;
    }
}

// ---------- gemm2_tile: [128 x 256] @ [256 x 128], BK=64, fp32 out ----------
__global__ __launch_bounds__(256) void gemm2_tile(
    const unsigned short* __restrict__ meanC, const unsigned short* __restrict__ comb,
    const float* __restrict__ bnA, const float* __restrict__ bnB,
    const unsigned short* __restrict__ W2catB, const float* __restrict__ bias2,
    float* __restrict__ out) {
    __shared__ unsigned short ABs[16384];
    unsigned short* As = ABs;
    unsigned short* Bs = ABs + 8192;
    int tid = threadIdx.x;
    int wid = tid >> 6, lane = tid & 63;
    int quad = lane >> 4, m16 = lane & 15;
    int nb = blockIdx.x * 128;
    int mb = (wid & 1) * 64, fb = (wid >> 1) * 64;
    f32x4 acc[4][4];
#pragma unroll
    for (int mi = 0; mi < 4; ++mi)
#pragma unroll
        for (int fi = 0; fi < 4; ++fi) acc[mi][fi] = (f32x4){0.f, 0.f, 0.f, 0.f};

    for (int kc = 0; kc < 4; ++kc) {
        __syncthreads();
#pragma unroll
        for (int it = 0; it < 4; ++it) {
            int idx = it * 256 + tid;
            int row = idx >> 3, c8 = idx & 7;
            int s = c8 >> 2, q = c8 & 3;
            int gr = min(nb + row, NN - 1);
            uint4 v;
            if (kc < 2) {
                v = *(const uint4*)(meanC + (size_t)gr * DD + kc * 64 + c8 * 8);
            } else {
                int cb = (kc - 2) * 64 + c8 * 8;
                uint4 c4 = *(const uint4*)(comb + (size_t)gr * DD + cb);
                float4 a0 = *(const float4*)&bnA[cb], a1 = *(const float4*)&bnA[cb + 4];
                float4 b0 = *(const float4*)&bnB[cb], b1 = *(const float4*)&bnB[cb + 4];
                v.x = pack2(a0.x * b2lo(c4.x) + b0.x, a0.y * b2hi(c4.x) + b0.y);
                v.y = pack2(a0.z * b2lo(c4.y) + b0.z, a0.w * b2hi(c4.y) + b0.w);
                v.z = pack2(a1.x * b2lo(c4.z) + b1.x, a1.y * b2hi(c4.z) + b1.y);
                v.w = pack2(a1.z * b2lo(c4.w) + b1.z, a1.w * b2hi(c4.w) + b1.w);
            }
            *(uint4*)&As[(((s * 128 + row) * 4) + q) * 8] = v;
        }
#pragma unroll
        for (int it = 0; it < 4; ++it) {
            int idx = it * 256 + tid;
            int f = idx >> 3, c8 = idx & 7;
            int s = c8 >> 2, q = c8 & 3;
            uint4 v = *(const uint4*)(W2catB + (size_t)f * 256 + kc * 64 + c8 * 8);
            *(uint4*)&Bs[(((s * 128 + f) * 4) + q) * 8] = v;
        }
        __syncthreads();
#pragma unroll
        for (int s = 0; s < 2; ++s) {
            bf16x8 av[4], bv[4];
#pragma unroll
            for (int mi = 0; mi < 4; ++mi)
                av[mi] = *(const bf16x8*)&As[(((s * 128 + mb + mi * 16 + m16) * 4) + quad) * 8];
#pragma unroll
            for (int fi = 0; fi < 4; ++fi)
                bv[fi] = *(const bf16x8*)&Bs[(((s * 128 + fb + fi * 16 + m16) * 4) + quad) * 8];
#pragma unroll
            for (int mi = 0; mi < 4; ++mi)
#pragma unroll
                for (int fi = 0; fi < 4; ++fi)
                    acc[mi][fi] = __builtin_amdgcn_mfma_f32_16x16x32_bf16(av[mi], bv[fi], acc[mi][fi], 0, 0, 0);
        }
    }
#pragma unroll
    for (int fi = 0; fi < 4; ++fi) {
        int f = fb + fi * 16 + m16;
        float bb = bias2[f];
#pragma unroll
        for (int mi = 0; mi < 4; ++mi) {
#pragma unroll
            for (int r = 0; r < 4; ++r) {
                int row = nb + mb + mi * 16 + quad * 4 + r;
                if (row < NN) out[(size_t)row * DD + f] = acc[mi][fi][r] + bb;
            }
        }
    }
}

extern "C" void kernel_launch(void* const* d_in, const int* in_sizes, int n_in,
                              void* d_out, int out_size, void* d_ws, size_t ws_size,
                              hipStream_t stream) {
    const float* feat = (const float*)d_in[0];
    const int* e0 = (const int*)d_in[1];
    const int* e1 = (const int*)d_in[2];
    const int* e2 = (const int*)d_in[3];
    const float* Wl0 = (const float*)d_in[4];
    const float* bl0 = (const float*)d_in[5];
    const float* Wr0 = (const float*)d_in[6];
    const float* Wl1 = (const float*)d_in[7];
    const float* bl1 = (const float*)d_in[8];
    const float* Wr1 = (const float*)d_in[9];
    const float* Wl2 = (const float*)d_in[10];
    const float* bl2 = (const float*)d_in[11];
    const float* Wr2 = (const float*)d_in[12];
    const float* Wla = (const float*)d_in[13];
    const float* bla = (const float*)d_in[14];
    const float* Wra = (const float*)d_in[15];
    const float* Wf  = (const float*)d_in[16];
    const float* bfv = (const float*)d_in[17];
    const float* Wrf = (const float*)d_in[18];
    const float* gamma = (const float*)d_in[19];
    const float* beta  = (const float*)d_in[20];
    const float* wt    = (const float*)d_in[21];

    int* deg      = (int*)d_ws;              // 3*NN
    int* rowstart = deg + 3 * NN;            // 3*NN
    int* fillpos  = rowstart + 3 * NN;       // 3*NN
    int* csr      = fillpos + 3 * NN;        // 3*NE
    int* bsum     = csr + 3 * NE;            // 147 (pad 160)
    float* partials = (float*)(bsum + 160);  // 256*NBLKG
    float* bias1  = partials + 256 * NBLKG;  // 128
    float* bias2  = bias1 + 128;             // 128
    float* bnA    = bias2 + 128;             // 128
    float* bnB    = bnA + 128;               // 128
    unsigned short* WcatB  = (unsigned short*)(bnB + 128);   // 128*640
    unsigned short* W2catB = WcatB + 81920;                  // 128*256
    unsigned short* comb   = W2catB + 32768;                 // NN*128
    unsigned short* featB  = comb + (size_t)NN * DD;         // NN*128
    unsigned short* meanB  = featB + (size_t)NN * DD;        // NN*512
    unsigned short* meanC  = meanB + (size_t)NN * 512;       // NN*128

    hipMemsetAsync(deg, 0, (size_t)3 * NN * sizeof(int), stream);

    feat_to_bf16<<<6250, 256, 0, stream>>>(feat, featB);
    prep_weights<<<449, 256, 0, stream>>>(Wl0, bl0, Wr0, Wl1, bl1, Wr1, Wl2, bl2, Wr2,
                                          Wla, bla, Wra, Wf, bfv, Wrf, wt,
                                          WcatB, bias1, W2catB, bias2);
    count_deg<<<3516, 256, 0, stream>>>(e0, e1, e2, deg);
    scan_local<<<147, 256, 0, stream>>>(deg, rowstart, bsum);
    scan_bsum<<<1, 64, 0, stream>>>(bsum);
    scan_fix<<<147, 256, 0, stream>>>(rowstart, fillpos, bsum);
    fill_csr<<<3516, 256, 0, stream>>>(e0, e1, e2, fillpos, csr);

    gather1<<<25000, 256, 0, stream>>>(featB, deg, rowstart, csr, meanB);
    gemm1_tile<<<NBLKG, 256, 0, stream>>>(meanB, featB, WcatB, bias1, comb, partials);
    bnfin<<<128, 256, 0, stream>>>(partials, gamma, beta, bnA, bnB);
    gather2<<<25000, 256, 0, stream>>>(comb, deg, rowstart, csr, bnA, bnB, meanC);
    gemm2_tile<<<NBLKG, 256, 0, stream>>>(meanC, comb, bnA, bnB, W2catB, bias2,
                                          (float*)d_out);
}